// Round 6
// baseline (11.580 us; speedup 1.0000x reference)
//
#include <hip/hip_runtime.h>
#include <math.h>

#define BATCH  8
#define NPRED  4096
#define MGT    2048
#define UU     4096
#define SPB    8                     // pred-slice blocks per batch
#define NPROD  (BATCH * SPB)         // 64 producer blocks
#define PSLICE (NPRED / SPB)         // 512 preds per block
#define WREG   (PSLICE / 4)          // 128: per-wave compaction region capacity
#define GPT    (MGT / 256)           // 8 gt boxes per thread
#define MAGIC  0xC0FFEE00u
#define STRIDE 16                    // u64 stride -> 128 B per slot (own cache line)
// slot index = w*64 + blk  (w = wave 0..3, blk = producer 0..63); 256 slots = 32 KB ws

__global__ __launch_bounds__(256) void fused_kernel(
    const float4* __restrict__ pred_boxes,     // [B*N]
    const int2*   __restrict__ pred_classes2,  // [B*N/2]
    const float4* __restrict__ gt_boxes,       // [B*M]
    const float4* __restrict__ union_scores4,  // [U/4]
    const int4*   __restrict__ union_classes4, // [U/4]
    unsigned long long* __restrict__ slots,    // ws: 256 slots, 128 B apart
    float* __restrict__ out)                   // [2] = {max_prob_t, max_iou_t}
{
    const int tid = threadIdx.x;
    const int blk = blockIdx.x;

    if (blk < NPROD) {
        // ---------- producer: (batch b, pred slice psub) vs ALL gts of b ----------
        __shared__ float4 plist[4][WREG];   // wave-private compaction regions
        __shared__ float  parea[4][WREG];
        __shared__ int    lcnt[4];

        const int w    = tid >> 6;
        const int lane = tid & 63;
        const int b    = blk >> 3;
        const int psub = blk & 7;

        // ---- issue ALL loads up front (11 independent vmem ops, one latency hop) ----
        const int  cbase = b * (NPRED / 2) + psub * (PSLICE / 2) + tid;  // int2 idx
        const int2 cl    = pred_classes2[cbase];
        const float4 bx0 = pred_boxes[cbase * 2 + 0];
        const float4 bx1 = pred_boxes[cbase * 2 + 1];

        float4 g[GPT];
        #pragma unroll
        for (int k = 0; k < GPT; ++k)
            g[k] = gt_boxes[b * MGT + k * 256 + tid];

        float ga[GPT];
        #pragma unroll
        for (int k = 0; k < GPT; ++k)
            ga[k] = (g[k].z - g[k].x) * (g[k].w - g[k].y);  // zeroed invalid gt -> iou 0

        // ---- per-wave compaction: counter init + LDS atomics are same-wave DS ops
        // (in program order -> ordered); regions are wave-private, so the ONLY
        // block-wide barrier needed is the one before the IoU loop. ----
        if (lane == 0) lcnt[w] = 0;
        if (cl.x == 0) { int p = atomicAdd(&lcnt[w], 1); plist[w][p] = bx0; parea[w][p] = (bx0.z - bx0.x) * (bx0.w - bx0.y); }
        if (cl.y == 0) { int p = atomicAdd(&lcnt[w], 1); plist[w][p] = bx1; parea[w][p] = (bx1.z - bx1.x) * (bx1.w - bx1.y); }
        __syncthreads();

        // ---- IoU: this thread's 8 gts vs all compacted persons (4 wave regions) ----
        float best[GPT];
        #pragma unroll
        for (int k = 0; k < GPT; ++k) best[k] = 0.0f;

        #pragma unroll
        for (int ww = 0; ww < 4; ++ww) {
            const int cnt = lcnt[ww];            // uniform -> LDS broadcast reads
            for (int j = 0; j < cnt; ++j) {
                const float4 p  = plist[ww][j];
                const float  ap = parea[ww][j];
                #pragma unroll
                for (int k = 0; k < GPT; ++k) {
                    float iw = fminf(p.z, g[k].z) - fmaxf(p.x, g[k].x);
                    float ih = fminf(p.w, g[k].w) - fmaxf(p.y, g[k].y);
                    iw = fmaxf(iw, 0.0f); ih = fmaxf(ih, 0.0f);
                    const float inter = iw * ih;
                    const float uni   = ap + ga[k] - inter;
                    best[k] = fmaxf(best[k], inter * __builtin_amdgcn_rcpf(fmaxf(uni, 1e-9f)));
                }
            }
        }

        float bestv = best[0];
        #pragma unroll
        for (int k = 1; k < GPT; ++k) bestv = fmaxf(bestv, best[k]);

        // per-wave max reduce, then wave lane0 signals its own slot immediately
        #pragma unroll
        for (int off = 32; off >= 1; off >>= 1)
            bestv = fmaxf(bestv, __shfl_xor(bestv, off));
        if (lane == 0) {
            // iou >= 0 -> raw float bits are uint-monotone; exact payload
            const unsigned long long v =
                ((unsigned long long)MAGIC << 32) | (unsigned long long)__float_as_uint(bestv);
            __hip_atomic_store(&slots[(w * 64 + blk) * STRIDE], v,
                               __ATOMIC_RELAXED, __HIP_MEMORY_SCOPE_AGENT);
        }
    } else {
        // ---------- finalizer: union masked max (overlaps producers), then collect ----------
        __shared__ float pmax[4];
        float mp = -INFINITY;
        #pragma unroll
        for (int s = 0; s < UU / (256 * 4); ++s) {          // 4 sub-steps
            const int i = s * 256 + tid;
            const int4   c = union_classes4[i];
            const float4 v = union_scores4[i];
            if (c.x == 0) mp = fmaxf(mp, v.x);
            if (c.y == 0) mp = fmaxf(mp, v.y);
            if (c.z == 0) mp = fmaxf(mp, v.z);
            if (c.w == 0) mp = fmaxf(mp, v.w);
        }
        #pragma unroll
        for (int off = 32; off >= 1; off >>= 1)
            mp = fmaxf(mp, __shfl_xor(mp, off));
        if ((tid & 63) == 0) pmax[tid >> 6] = mp;
        __syncthreads();
        if (tid == 0)
            out[0] = fmaxf(fmaxf(pmax[0], pmax[1]), fmaxf(pmax[2], pmax[3]));

        // wave 0: lane l polls the 4 per-wave slots of producer l (each its own line)
        if (tid < 64) {
            unsigned long long v0, v1, v2, v3;
            do {
                v0 = __hip_atomic_load(&slots[(0 * 64 + tid) * STRIDE], __ATOMIC_RELAXED, __HIP_MEMORY_SCOPE_AGENT);
                v1 = __hip_atomic_load(&slots[(1 * 64 + tid) * STRIDE], __ATOMIC_RELAXED, __HIP_MEMORY_SCOPE_AGENT);
                v2 = __hip_atomic_load(&slots[(2 * 64 + tid) * STRIDE], __ATOMIC_RELAXED, __HIP_MEMORY_SCOPE_AGENT);
                v3 = __hip_atomic_load(&slots[(3 * 64 + tid) * STRIDE], __ATOMIC_RELAXED, __HIP_MEMORY_SCOPE_AGENT);
            } while (((unsigned int)(v0 >> 32) != MAGIC) || ((unsigned int)(v1 >> 32) != MAGIC) ||
                     ((unsigned int)(v2 >> 32) != MAGIC) || ((unsigned int)(v3 >> 32) != MAGIC));
            // reset so the next replay starts from a non-magic state
            __hip_atomic_store(&slots[(0 * 64 + tid) * STRIDE], 0ULL, __ATOMIC_RELAXED, __HIP_MEMORY_SCOPE_AGENT);
            __hip_atomic_store(&slots[(1 * 64 + tid) * STRIDE], 0ULL, __ATOMIC_RELAXED, __HIP_MEMORY_SCOPE_AGENT);
            __hip_atomic_store(&slots[(2 * 64 + tid) * STRIDE], 0ULL, __ATOMIC_RELAXED, __HIP_MEMORY_SCOPE_AGENT);
            __hip_atomic_store(&slots[(3 * 64 + tid) * STRIDE], 0ULL, __ATOMIC_RELAXED, __HIP_MEMORY_SCOPE_AGENT);

            unsigned int q = max(max((unsigned int)v0, (unsigned int)v1),
                                 max((unsigned int)v2, (unsigned int)v3));
            // max over the 8 pred-slices of each batch (lanes 8b..8b+7)
            q = max(q, (unsigned int)__shfl_xor((int)q, 1, 8));
            q = max(q, (unsigned int)__shfl_xor((int)q, 2, 8));
            q = max(q, (unsigned int)__shfl_xor((int)q, 4, 8));
            // fixed-order sum over the 8 batch maxima -> bitwise deterministic
            float s = 0.0f;
            #pragma unroll
            for (int i = 0; i < 8; ++i)
                s += __uint_as_float((unsigned int)__shfl((int)q, 8 * i, 64));
            if (tid == 0)
                out[1] = s * 0.125f;                        // mean over batches
        }
    }
}

extern "C" void kernel_launch(void* const* d_in, const int* in_sizes, int n_in,
                              void* d_out, int out_size, void* d_ws, size_t ws_size,
                              hipStream_t stream) {
    const float4* pred_boxes    = (const float4*)d_in[0];
    // d_in[1] = pred_scores (unused by the reference result)
    const int2*   pred_classes2 = (const int2*)d_in[2];
    const float4* gt_boxes      = (const float4*)d_in[3];
    const float4* union_scores4 = (const float4*)d_in[4];
    const int4*   union_classes4= (const int4*)d_in[5];
    float* out = (float*)d_out;
    unsigned long long* slots = (unsigned long long*)d_ws;  // 256 x 128 B lines (32 KB)

    fused_kernel<<<NPROD + 1, 256, 0, stream>>>(pred_boxes, pred_classes2, gt_boxes,
                                                union_scores4, union_classes4, slots, out);
}